// Round 1
// baseline (536.060 us; speedup 1.0000x reference)
//
#include <hip/hip_runtime.h>

#define NB 16
#define NCIN 256
#define NL 2048
#define NHID 512
#define NM 512
#define NLP 1024

// ---------------- K1: grouped conv1x1 + bias + relu + maxpool2 -> h[16,512,1024]
__global__ __launch_bounds__(256) void k1_conv_pool(
    const float* __restrict__ x, const float* __restrict__ w1,
    const float* __restrict__ b1, float* __restrict__ h)
{
    const int bid = blockIdx.x;
    const int lc = bid & 7;          // l-chunk (8 x 256)
    const int ot = (bid >> 3) & 3;   // o-tile (4 x 64)
    const int g  = (bid >> 5) & 1;
    const int b  = bid >> 6;

    __shared__ float wlds[64 * 128];
    for (int idx = threadIdx.x; idx < 64 * 128; idx += 256) {
        const int o = idx >> 7, k = idx & 127;
        wlds[idx] = w1[(g * 256 + ot * 64 + o) * 128 + k];
    }
    __syncthreads();

    const int lane = threadIdx.x & 63;
    const int slot = threadIdx.x >> 6;
    const int l0 = lc * 256 + lane * 4;
    const float* xb = x + ((size_t)b * NCIN + g * 128) * NL + l0;

    float4 acc[16];
    #pragma unroll
    for (int j = 0; j < 16; ++j) acc[j] = make_float4(0.f, 0.f, 0.f, 0.f);

    for (int k = 0; k < 128; ++k) {
        const float4 xv = *(const float4*)(xb + (size_t)k * NL);
        const float* wrow = wlds + slot * 16 * 128 + k;
        #pragma unroll
        for (int j = 0; j < 16; ++j) {
            const float w = wrow[j * 128];   // broadcast across wave: conflict-free
            acc[j].x = fmaf(w, xv.x, acc[j].x);
            acc[j].y = fmaf(w, xv.y, acc[j].y);
            acc[j].z = fmaf(w, xv.z, acc[j].z);
            acc[j].w = fmaf(w, xv.w, acc[j].w);
        }
    }

    const int lp0 = l0 >> 1;
    #pragma unroll
    for (int j = 0; j < 16; ++j) {
        const int c = g * 256 + ot * 64 + slot * 16 + j;
        const float bias = b1[c];
        // relu(max(a,b)+bias) == maxpool(relu(conv+bias))
        const float h0 = fmaxf(fmaxf(acc[j].x, acc[j].y) + bias, 0.f);
        const float h1 = fmaxf(fmaxf(acc[j].z, acc[j].w) + bias, 0.f);
        *(float2*)(h + ((size_t)b * NHID + c) * NLP + lp0) = make_float2(h0, h1);
    }
}

// ---------------- K2: S[r][m] = sum_l h[r][l] * P[m][l]  (r=8192, m=512, K=1024)
__global__ __launch_bounds__(256) void k2_scores(
    const float* __restrict__ h, const float* __restrict__ P,
    float* __restrict__ S)
{
    const int mt = blockIdx.x & 3;
    const int rt = blockIdx.x >> 2;
    const int r0 = rt * 128, m0 = mt * 128;

    __shared__ float As[128 * 17];
    __shared__ float Bs[128 * 17];

    const int tx = threadIdx.x & 15, ty = threadIdx.x >> 4;

    float acc[8][8];
    #pragma unroll
    for (int i = 0; i < 8; ++i)
        #pragma unroll
        for (int j = 0; j < 8; ++j) acc[i][j] = 0.f;

    for (int k0 = 0; k0 < 1024; k0 += 16) {
        for (int t = threadIdx.x; t < 512; t += 256) {
            const int row = t >> 2, c4 = (t & 3) << 2;
            const float4 av = *(const float4*)(h + (size_t)(r0 + row) * 1024 + k0 + c4);
            As[row * 17 + c4 + 0] = av.x; As[row * 17 + c4 + 1] = av.y;
            As[row * 17 + c4 + 2] = av.z; As[row * 17 + c4 + 3] = av.w;
            const float4 bv = *(const float4*)(P + (size_t)(m0 + row) * 1024 + k0 + c4);
            Bs[row * 17 + c4 + 0] = bv.x; Bs[row * 17 + c4 + 1] = bv.y;
            Bs[row * 17 + c4 + 2] = bv.z; Bs[row * 17 + c4 + 3] = bv.w;
        }
        __syncthreads();
        #pragma unroll
        for (int kk = 0; kk < 16; ++kk) {
            float a[8], bb[8];
            #pragma unroll
            for (int i = 0; i < 8; ++i) a[i] = As[(ty + 16 * i) * 17 + kk];
            #pragma unroll
            for (int j = 0; j < 8; ++j) bb[j] = Bs[(tx + 16 * j) * 17 + kk];
            #pragma unroll
            for (int i = 0; i < 8; ++i)
                #pragma unroll
                for (int j = 0; j < 8; ++j)
                    acc[i][j] = fmaf(a[i], bb[j], acc[i][j]);
        }
        __syncthreads();
    }

    #pragma unroll
    for (int i = 0; i < 8; ++i)
        #pragma unroll
        for (int j = 0; j < 8; ++j)
            S[(size_t)(r0 + ty + 16 * i) * 512 + m0 + tx + 16 * j] = acc[i][j];
}

// ---------------- K2.5: row softmax over M=512, in place (8192 rows)
__global__ __launch_bounds__(256) void k_softmax(float* __restrict__ S)
{
    const int row = blockIdx.x * 4 + (threadIdx.x >> 6);
    const int lane = threadIdx.x & 63;
    float* p = S + (size_t)row * 512;

    float v[8];
    #pragma unroll
    for (int j = 0; j < 8; ++j) v[j] = p[lane + 64 * j];

    float mx = v[0];
    #pragma unroll
    for (int j = 1; j < 8; ++j) mx = fmaxf(mx, v[j]);
    for (int off = 32; off > 0; off >>= 1) mx = fmaxf(mx, __shfl_xor(mx, off));

    float sum = 0.f;
    #pragma unroll
    for (int j = 0; j < 8; ++j) { v[j] = __expf(v[j] - mx); sum += v[j]; }
    for (int off = 32; off > 0; off >>= 1) sum += __shfl_xor(sum, off);

    const float inv = 1.f / sum;
    #pragma unroll
    for (int j = 0; j < 8; ++j) p[lane + 64 * j] = v[j] * inv;
}

// ---------------- K3: h2[r][n] = sum_m A[r][m] * P[m][n]  (r=8192, n=1024, K=512)
__global__ __launch_bounds__(256) void k3_retrieve(
    const float* __restrict__ A, const float* __restrict__ P,
    float* __restrict__ h2)
{
    const int nt = blockIdx.x & 7;
    const int rt = blockIdx.x >> 3;
    const int r0 = rt * 128, n0 = nt * 128;

    __shared__ float As[128 * 17];
    __shared__ float Bs[16 * 128];

    const int tx = threadIdx.x & 15, ty = threadIdx.x >> 4;

    float acc[8][8];
    #pragma unroll
    for (int i = 0; i < 8; ++i)
        #pragma unroll
        for (int j = 0; j < 8; ++j) acc[i][j] = 0.f;

    for (int k0 = 0; k0 < 512; k0 += 16) {
        for (int t = threadIdx.x; t < 512; t += 256) {
            const int row = t >> 2, c4 = (t & 3) << 2;
            const float4 av = *(const float4*)(A + (size_t)(r0 + row) * 512 + k0 + c4);
            As[row * 17 + c4 + 0] = av.x; As[row * 17 + c4 + 1] = av.y;
            As[row * 17 + c4 + 2] = av.z; As[row * 17 + c4 + 3] = av.w;
        }
        for (int t = threadIdx.x; t < 512; t += 256) {
            const int kk = t >> 5, c4 = (t & 31) << 2;
            *(float4*)(Bs + kk * 128 + c4) =
                *(const float4*)(P + (size_t)(k0 + kk) * 1024 + n0 + c4);
        }
        __syncthreads();
        #pragma unroll
        for (int kk = 0; kk < 16; ++kk) {
            float a[8], bb[8];
            #pragma unroll
            for (int i = 0; i < 8; ++i) a[i] = As[(ty + 16 * i) * 17 + kk];
            #pragma unroll
            for (int j = 0; j < 8; ++j) bb[j] = Bs[kk * 128 + tx + 16 * j];
            #pragma unroll
            for (int i = 0; i < 8; ++i)
                #pragma unroll
                for (int j = 0; j < 8; ++j)
                    acc[i][j] = fmaf(a[i], bb[j], acc[i][j]);
        }
        __syncthreads();
    }

    #pragma unroll
    for (int i = 0; i < 8; ++i)
        #pragma unroll
        for (int j = 0; j < 8; ++j)
            h2[(size_t)(r0 + ty + 16 * i) * 1024 + n0 + tx + 16 * j] = acc[i][j];
}

// ---------------- K4: grouped convT(k=2,s=2) + bias + relu + residual
__global__ __launch_bounds__(256) void k4_convT(
    const float* __restrict__ h2, const float* __restrict__ wT,
    const float* __restrict__ bT, const float* __restrict__ x,
    const float* __restrict__ RZ, float* __restrict__ out)
{
    const int bid = blockIdx.x;
    const int lc = bid & 3;          // lp-chunk (4 x 256)
    const int ot = (bid >> 2) & 3;   // ok-tile (4 x 64) over (o,k) pairs
    const int g  = (bid >> 4) & 1;
    const int b  = bid >> 5;

    __shared__ float wlds[64 * 129];

    const int lane = threadIdx.x & 63;
    const int slot = threadIdx.x >> 6;
    const int lp0 = lc * 256 + lane * 4;
    const int okbase = ot * 64;

    float4 acc[16];
    #pragma unroll
    for (int j = 0; j < 16; ++j) acc[j] = make_float4(0.f, 0.f, 0.f, 0.f);

    for (int kc = 0; kc < 2; ++kc) {
        __syncthreads();
        for (int idx = threadIdx.x; idx < 64 * 128; idx += 256) {
            const int i = idx >> 6, ok = idx & 63;
            // A[(o,k)][i] = wT[(g*256+i)*256 + okbase + ok]
            wlds[ok * 129 + i] = wT[(size_t)(g * 256 + kc * 128 + i) * 256 + okbase + ok];
        }
        __syncthreads();
        const float* hb = h2 + ((size_t)b * NHID + g * 256 + kc * 128) * NLP + lp0;
        for (int i = 0; i < 128; ++i) {
            const float4 xv = *(const float4*)(hb + (size_t)i * NLP);
            const float* wrow = wlds + slot * 16 * 129 + i;
            #pragma unroll
            for (int j = 0; j < 16; ++j) {
                const float w = wrow[j * 129];   // broadcast
                acc[j].x = fmaf(w, xv.x, acc[j].x);
                acc[j].y = fmaf(w, xv.y, acc[j].y);
                acc[j].z = fmaf(w, xv.z, acc[j].z);
                acc[j].w = fmaf(w, xv.w, acc[j].w);
            }
        }
    }

    const float rz = RZ[0];
    #pragma unroll
    for (int j2 = 0; j2 < 8; ++j2) {
        const int o = ((okbase + slot * 16) >> 1) + j2;  // okbase+slot*16 even
        const int c = g * 128 + o;
        const float bias = bT[c];
        const float4 a0 = acc[2 * j2];      // k=0 taps
        const float4 a1 = acc[2 * j2 + 1];  // k=1 taps
        const size_t base = ((size_t)b * NCIN + c) * NL + 2 * lp0;
        const float4 x0 = *(const float4*)(x + base);
        const float4 x1 = *(const float4*)(x + base + 4);
        float4 o0, o1;
        o0.x = x0.x + rz * fmaxf(a0.x + bias, 0.f);
        o0.y = x0.y + rz * fmaxf(a1.x + bias, 0.f);
        o0.z = x0.z + rz * fmaxf(a0.y + bias, 0.f);
        o0.w = x0.w + rz * fmaxf(a1.y + bias, 0.f);
        o1.x = x1.x + rz * fmaxf(a0.z + bias, 0.f);
        o1.y = x1.y + rz * fmaxf(a1.z + bias, 0.f);
        o1.z = x1.z + rz * fmaxf(a0.w + bias, 0.f);
        o1.w = x1.w + rz * fmaxf(a1.w + bias, 0.f);
        *(float4*)(out + base) = o0;
        *(float4*)(out + base + 4) = o1;
    }
}

extern "C" void kernel_launch(void* const* d_in, const int* in_sizes, int n_in,
                              void* d_out, int out_size, void* d_ws, size_t ws_size,
                              hipStream_t stream) {
    (void)in_sizes; (void)n_in; (void)out_size; (void)ws_size;
    const float* x  = (const float*)d_in[0];
    const float* w1 = (const float*)d_in[1];
    const float* b1 = (const float*)d_in[2];
    const float* P  = (const float*)d_in[3];
    const float* wT = (const float*)d_in[4];
    const float* bT = (const float*)d_in[5];
    const float* RZ = (const float*)d_in[6];
    float* out = (float*)d_out;

    float* h = (float*)d_ws;                       // 8,388,608 floats (32 MB)
    float* S = h + (size_t)NB * NHID * NLP;        // 4,194,304 floats (16 MB)
    // h2 reuses h's buffer (h is dead after K2)

    hipLaunchKernelGGL(k1_conv_pool, dim3(1024), dim3(256), 0, stream, x, w1, b1, h);
    hipLaunchKernelGGL(k2_scores,    dim3(256),  dim3(256), 0, stream, h, P, S);
    hipLaunchKernelGGL(k_softmax,    dim3(2048), dim3(256), 0, stream, S);
    hipLaunchKernelGGL(k3_retrieve,  dim3(512),  dim3(256), 0, stream, S, P, h);
    hipLaunchKernelGGL(k4_convT,     dim3(512),  dim3(256), 0, stream, h, wT, bT, x, RZ, out);
}

// Round 2
// 266.048 us; speedup vs baseline: 2.0149x; 2.0149x over previous
//
#include <hip/hip_runtime.h>

#define NB 16
#define NCIN 256
#define NL 2048
#define NHID 512
#define NM 512
#define NLP 1024
#define BK 64

typedef short bf16x8 __attribute__((ext_vector_type(8)));
typedef float f32x4 __attribute__((ext_vector_type(4)));
typedef __attribute__((address_space(1))) const unsigned int gas_u32;
typedef __attribute__((address_space(3))) unsigned int las_u32;

__device__ __forceinline__ unsigned short f2bf(float f) {
    unsigned int u = __builtin_bit_cast(unsigned int, f);
    return (unsigned short)((u + 0x7FFFu + ((u >> 16) & 1u)) >> 16);
}

// ---------------- prep: P fp32 -> Pb bf16 [512,1024] and Ptb bf16 [1024,512]
__global__ __launch_bounds__(256) void k_prep(
    const float* __restrict__ P, unsigned short* __restrict__ Pb,
    unsigned short* __restrict__ Ptb)
{
    __shared__ unsigned short tbuf[64][65];
    const int mt = blockIdx.x >> 4;   // 8 tiles over M=512
    const int lt = blockIdx.x & 15;   // 16 tiles over L=1024
    for (int i = threadIdx.x; i < 4096; i += 256) {
        const int r = i >> 6, c = i & 63;
        const unsigned short b = f2bf(P[(size_t)(mt * 64 + r) * 1024 + lt * 64 + c]);
        Pb[(size_t)(mt * 64 + r) * 1024 + lt * 64 + c] = b;
        tbuf[c][r] = b;
    }
    __syncthreads();
    for (int i = threadIdx.x; i < 4096; i += 256) {
        const int r = i >> 6, c = i & 63;   // r: l within tile, c: m within tile
        Ptb[(size_t)(lt * 64 + r) * 512 + mt * 64 + c] = tbuf[r][c];
    }
}

// ---------------- K1: grouped conv1x1 + bias + relu + maxpool2 -> hb bf16 [16,512,1024]
__global__ __launch_bounds__(256) void k1_conv_pool(
    const float* __restrict__ x, const float* __restrict__ w1,
    const float* __restrict__ b1, unsigned short* __restrict__ hb)
{
    const int bid = blockIdx.x;
    const int lc = bid & 7;          // l-chunk (8 x 256)
    const int ot = (bid >> 3) & 3;   // o-tile (4 x 64)
    const int g  = (bid >> 5) & 1;
    const int b  = bid >> 6;

    __shared__ float wlds[64 * 128];
    for (int idx = threadIdx.x; idx < 64 * 128; idx += 256) {
        const int o = idx >> 7, k = idx & 127;
        wlds[idx] = w1[(g * 256 + ot * 64 + o) * 128 + k];
    }
    __syncthreads();

    const int lane = threadIdx.x & 63;
    const int slot = threadIdx.x >> 6;
    const int l0 = lc * 256 + lane * 4;
    const float* xb = x + ((size_t)b * NCIN + g * 128) * NL + l0;

    float4 acc[16];
    #pragma unroll
    for (int j = 0; j < 16; ++j) acc[j] = make_float4(0.f, 0.f, 0.f, 0.f);

    for (int k = 0; k < 128; ++k) {
        const float4 xv = *(const float4*)(xb + (size_t)k * NL);
        const float* wrow = wlds + slot * 16 * 128 + k;
        #pragma unroll
        for (int j = 0; j < 16; ++j) {
            const float w = wrow[j * 128];   // broadcast across wave: conflict-free
            acc[j].x = fmaf(w, xv.x, acc[j].x);
            acc[j].y = fmaf(w, xv.y, acc[j].y);
            acc[j].z = fmaf(w, xv.z, acc[j].z);
            acc[j].w = fmaf(w, xv.w, acc[j].w);
        }
    }

    const int lp0 = l0 >> 1;
    #pragma unroll
    for (int j = 0; j < 16; ++j) {
        const int c = g * 256 + ot * 64 + slot * 16 + j;
        const float bias = b1[c];
        const float h0 = fmaxf(fmaxf(acc[j].x, acc[j].y) + bias, 0.f);
        const float h1 = fmaxf(fmaxf(acc[j].z, acc[j].w) + bias, 0.f);
        ushort2 o2; o2.x = f2bf(h0); o2.y = f2bf(h1);
        *(ushort2*)(hb + ((size_t)b * NHID + c) * NLP + lp0) = o2;
    }
}

// ---------------- gemm_bt: C[M,N] fp32 = A[M,K]bf16 . B[N,K]bf16^T  (m97 structure)
__global__ __launch_bounds__(256) void gemm_bt(
    const unsigned short* __restrict__ A, const unsigned short* __restrict__ B,
    float* __restrict__ C, int M, int N, int K, int ntiles)
{
    const int nt = blockIdx.x % ntiles;
    const int rt = blockIdx.x / ntiles;
    const int r0 = rt * 128, n0 = nt * 128;

    __shared__ unsigned short Asl[128 * BK];
    __shared__ unsigned short Bsl[128 * BK];

    const int t = threadIdx.x;
    const int lane = t & 63;
    const int wave = t >> 6;
    const int wm = wave & 1, wn = wave >> 1;
    const int q = lane >> 4, lm = lane & 15;

    f32x4 acc[4][4];
    #pragma unroll
    for (int i = 0; i < 4; ++i)
        #pragma unroll
        for (int j = 0; j < 4; ++j)
            #pragma unroll
            for (int r = 0; r < 4; ++r) acc[i][j][r] = 0.f;

    for (int k0 = 0; k0 < K; k0 += BK) {
        #pragma unroll
        for (int rd = 0; rd < 4; ++rd) {
            const int e = rd * 2048 + t * 8;          // bf16 element index in 128xBK tile
            const int row = e >> 6, col = e & 63;
            const unsigned short* ga = A + (size_t)(r0 + row) * K + k0 + col;
            __builtin_amdgcn_global_load_lds((gas_u32*)ga, (las_u32*)(Asl + e), 16, 0, 0);
            const unsigned short* gb = B + (size_t)(n0 + row) * K + k0 + col;
            __builtin_amdgcn_global_load_lds((gas_u32*)gb, (las_u32*)(Bsl + e), 16, 0, 0);
        }
        __syncthreads();
        #pragma unroll
        for (int kk = 0; kk < 2; ++kk) {
            bf16x8 af[4], bf[4];
            #pragma unroll
            for (int i = 0; i < 4; ++i)
                af[i] = *(const bf16x8*)(Asl + (wm * 64 + i * 16 + lm) * BK + kk * 32 + q * 8);
            #pragma unroll
            for (int j = 0; j < 4; ++j)
                bf[j] = *(const bf16x8*)(Bsl + (wn * 64 + j * 16 + lm) * BK + kk * 32 + q * 8);
            #pragma unroll
            for (int i = 0; i < 4; ++i)
                #pragma unroll
                for (int j = 0; j < 4; ++j)
                    acc[i][j] = __builtin_amdgcn_mfma_f32_16x16x32_bf16(af[i], bf[j], acc[i][j], 0, 0, 0);
        }
        __syncthreads();
    }

    #pragma unroll
    for (int i = 0; i < 4; ++i)
        #pragma unroll
        for (int j = 0; j < 4; ++j)
            #pragma unroll
            for (int r = 0; r < 4; ++r)
                C[(size_t)(r0 + wm * 64 + i * 16 + q * 4 + r) * N + n0 + wn * 64 + j * 16 + lm] = acc[i][j][r];
}

// ---------------- softmax over M=512, S fp32 -> Ab bf16 (8192 rows)
__global__ __launch_bounds__(256) void k_softmax(
    const float* __restrict__ S, unsigned short* __restrict__ Ab)
{
    const int row = blockIdx.x * 4 + (threadIdx.x >> 6);
    const int lane = threadIdx.x & 63;
    const float* p = S + (size_t)row * 512;
    unsigned short* po = Ab + (size_t)row * 512;

    float v[8];
    #pragma unroll
    for (int j = 0; j < 8; ++j) v[j] = p[lane + 64 * j];

    float mx = v[0];
    #pragma unroll
    for (int j = 1; j < 8; ++j) mx = fmaxf(mx, v[j]);
    for (int off = 32; off > 0; off >>= 1) mx = fmaxf(mx, __shfl_xor(mx, off));

    float sum = 0.f;
    #pragma unroll
    for (int j = 0; j < 8; ++j) { v[j] = __expf(v[j] - mx); sum += v[j]; }
    for (int off = 32; off > 0; off >>= 1) sum += __shfl_xor(sum, off);

    const float inv = 1.f / sum;
    #pragma unroll
    for (int j = 0; j < 8; ++j) po[lane + 64 * j] = f2bf(v[j] * inv);
}

// ---------------- K4: grouped convT(k=2,s=2) + bias + relu + residual
__global__ __launch_bounds__(256) void k4_convT(
    const float* __restrict__ h2, const float* __restrict__ wT,
    const float* __restrict__ bT, const float* __restrict__ x,
    const float* __restrict__ RZ, float* __restrict__ out)
{
    const int bid = blockIdx.x;
    const int lc = bid & 3;          // lp-chunk (4 x 256)
    const int ot = (bid >> 2) & 3;   // ok-tile (4 x 64) over (o,k) pairs
    const int g  = (bid >> 4) & 1;
    const int b  = bid >> 5;

    __shared__ float wlds[64 * 129];

    const int lane = threadIdx.x & 63;
    const int slot = threadIdx.x >> 6;
    const int lp0 = lc * 256 + lane * 4;
    const int okbase = ot * 64;

    float4 acc[16];
    #pragma unroll
    for (int j = 0; j < 16; ++j) acc[j] = make_float4(0.f, 0.f, 0.f, 0.f);

    for (int kc = 0; kc < 2; ++kc) {
        __syncthreads();
        for (int idx = threadIdx.x; idx < 64 * 128; idx += 256) {
            const int i = idx >> 6, ok = idx & 63;
            wlds[ok * 129 + i] = wT[(size_t)(g * 256 + kc * 128 + i) * 256 + okbase + ok];
        }
        __syncthreads();
        const float* hbp = h2 + ((size_t)b * NHID + g * 256 + kc * 128) * NLP + lp0;
        for (int i = 0; i < 128; ++i) {
            const float4 xv = *(const float4*)(hbp + (size_t)i * NLP);
            const float* wrow = wlds + slot * 16 * 129 + i;
            #pragma unroll
            for (int j = 0; j < 16; ++j) {
                const float w = wrow[j * 129];   // broadcast
                acc[j].x = fmaf(w, xv.x, acc[j].x);
                acc[j].y = fmaf(w, xv.y, acc[j].y);
                acc[j].z = fmaf(w, xv.z, acc[j].z);
                acc[j].w = fmaf(w, xv.w, acc[j].w);
            }
        }
    }

    const float rz = RZ[0];
    #pragma unroll
    for (int j2 = 0; j2 < 8; ++j2) {
        const int o = ((okbase + slot * 16) >> 1) + j2;
        const int c = g * 128 + o;
        const float bias = bT[c];
        const float4 a0 = acc[2 * j2];
        const float4 a1 = acc[2 * j2 + 1];
        const size_t base = ((size_t)b * NCIN + c) * NL + 2 * lp0;
        const float4 x0 = *(const float4*)(x + base);
        const float4 x1 = *(const float4*)(x + base + 4);
        float4 o0, o1;
        o0.x = x0.x + rz * fmaxf(a0.x + bias, 0.f);
        o0.y = x0.y + rz * fmaxf(a1.x + bias, 0.f);
        o0.z = x0.z + rz * fmaxf(a0.y + bias, 0.f);
        o0.w = x0.w + rz * fmaxf(a1.y + bias, 0.f);
        o1.x = x1.x + rz * fmaxf(a0.z + bias, 0.f);
        o1.y = x1.y + rz * fmaxf(a1.z + bias, 0.f);
        o1.z = x1.z + rz * fmaxf(a0.w + bias, 0.f);
        o1.w = x1.w + rz * fmaxf(a1.w + bias, 0.f);
        *(float4*)(out + base) = o0;
        *(float4*)(out + base + 4) = o1;
    }
}

extern "C" void kernel_launch(void* const* d_in, const int* in_sizes, int n_in,
                              void* d_out, int out_size, void* d_ws, size_t ws_size,
                              hipStream_t stream) {
    (void)in_sizes; (void)n_in; (void)out_size; (void)ws_size;
    const float* x  = (const float*)d_in[0];
    const float* w1 = (const float*)d_in[1];
    const float* b1 = (const float*)d_in[2];
    const float* P  = (const float*)d_in[3];
    const float* wT = (const float*)d_in[4];
    const float* bT = (const float*)d_in[5];
    const float* RZ = (const float*)d_in[6];
    float* out = (float*)d_out;

    // workspace layout (42 MB used):
    //   [0,16M)   hb  bf16 [8192,1024]     (dead after k2)
    //   [16,32M)  S   fp32 [8192,512]      (dead after softmax)
    //   [32,40M)  Ab  bf16 [8192,512]
    //   [40,41M)  Pb  bf16 [512,1024]
    //   [41,42M)  Ptb bf16 [1024,512]
    //   h2 fp32 [8192,1024] overlaps [0,32M)  (written by k3 after hb,S dead)
    char* ws = (char*)d_ws;
    unsigned short* hb  = (unsigned short*)ws;
    float*          S   = (float*)(ws + (16u << 20));
    unsigned short* Ab  = (unsigned short*)(ws + (32u << 20));
    unsigned short* Pb  = (unsigned short*)(ws + (40u << 20));
    unsigned short* Ptb = (unsigned short*)(ws + (41u << 20));
    float*          h2  = (float*)ws;

    hipLaunchKernelGGL(k_prep,       dim3(128),  dim3(256), 0, stream, P, Pb, Ptb);
    hipLaunchKernelGGL(k1_conv_pool, dim3(1024), dim3(256), 0, stream, x, w1, b1, hb);
    hipLaunchKernelGGL(gemm_bt,      dim3(256),  dim3(256), 0, stream, hb, Pb, S,
                       8192, 512, 1024, 4);
    hipLaunchKernelGGL(k_softmax,    dim3(2048), dim3(256), 0, stream, S, Ab);
    hipLaunchKernelGGL(gemm_bt,      dim3(512),  dim3(256), 0, stream, Ab, Ptb, h2,
                       8192, 1024, 512, 8);
    hipLaunchKernelGGL(k4_convT,     dim3(512),  dim3(256), 0, stream, h2, wT, bT, x, RZ, out);
}

// Round 3
// 187.459 us; speedup vs baseline: 2.8596x; 1.4192x over previous
//
#include <hip/hip_runtime.h>

#define NB 16
#define NCIN 256
#define NL 2048
#define NHID 512
#define NM 512
#define NLP 1024
#define BK 64

typedef short bf16x8 __attribute__((ext_vector_type(8)));
typedef unsigned short u16x8 __attribute__((ext_vector_type(8)));
typedef float f32x4 __attribute__((ext_vector_type(4)));
typedef __attribute__((address_space(1))) const unsigned int gas_u32;
typedef __attribute__((address_space(3))) unsigned int las_u32;

__device__ __forceinline__ unsigned short f2bf(float f) {
    unsigned int u = __builtin_bit_cast(unsigned int, f);
    return (unsigned short)((u + 0x7FFFu + ((u >> 16) & 1u)) >> 16);
}

// ---------------- prep: P fp32 -> Pb bf16 [512,1024] and Ptb bf16 [1024,512]
__global__ __launch_bounds__(256) void k_prep(
    const float* __restrict__ P, unsigned short* __restrict__ Pb,
    unsigned short* __restrict__ Ptb)
{
    __shared__ unsigned short tbuf[64][65];
    const int mt = blockIdx.x >> 4;
    const int lt = blockIdx.x & 15;
    for (int i = threadIdx.x; i < 4096; i += 256) {
        const int r = i >> 6, c = i & 63;
        const unsigned short b = f2bf(P[(size_t)(mt * 64 + r) * 1024 + lt * 64 + c]);
        Pb[(size_t)(mt * 64 + r) * 1024 + lt * 64 + c] = b;
        tbuf[c][r] = b;
    }
    __syncthreads();
    for (int i = threadIdx.x; i < 4096; i += 256) {
        const int r = i >> 6, c = i & 63;
        Ptb[(size_t)(lt * 64 + r) * 512 + mt * 64 + c] = tbuf[r][c];
    }
}

// ---------------- prep2: w1 -> bf16 cast; wT -> wTt bf16 [g][(o,kk)][i]
__global__ __launch_bounds__(256) void k_prep2(
    const float* __restrict__ w1, const float* __restrict__ wT,
    unsigned short* __restrict__ w1b, unsigned short* __restrict__ wTt)
{
    const int t = blockIdx.x * 256 + threadIdx.x;
    if (t < 65536) w1b[t] = f2bf(w1[t]);
    if (t < 131072) {
        const int g = t >> 16, ok = (t >> 8) & 255, i = t & 255;
        wTt[t] = f2bf(wT[((size_t)(g * 256 + i)) * 256 + ok]);
    }
}

// ---------------- k0: x fp32 [b,256,2048] -> xT bf16 [b,2048,256]
__global__ __launch_bounds__(256) void k0_xT(
    const float* __restrict__ x, unsigned short* __restrict__ xT)
{
    const int ct = blockIdx.x & 3;
    const int lt = (blockIdx.x >> 2) & 31;
    const int b  = blockIdx.x >> 7;
    __shared__ float tile[64 * 68];
    const int t = threadIdx.x;
    #pragma unroll
    for (int it = 0; it < 4; ++it) {
        const int idx = t + it * 256;
        const int ch = idx >> 4, f4 = idx & 15;
        const float4 v = *(const float4*)(x + ((size_t)(b * 256 + ct * 64 + ch)) * 2048 + lt * 64 + f4 * 4);
        *(float4*)(tile + ch * 68 + f4 * 4) = v;
    }
    __syncthreads();
    const int l = t >> 2, cq = t & 3;
    u16x8 o0, o1;
    #pragma unroll
    for (int k = 0; k < 8; ++k) o0[k] = f2bf(tile[(cq * 16 + k) * 68 + l]);
    #pragma unroll
    for (int k = 0; k < 8; ++k) o1[k] = f2bf(tile[(cq * 16 + 8 + k) * 68 + l]);
    unsigned short* dst = xT + ((size_t)(b * 2048 + lt * 64 + l)) * 256 + ct * 64 + cq * 16;
    *(u16x8*)dst = o0;
    *(u16x8*)(dst + 8) = o1;
}

// ---------------- k1_gemm: conv1x1 via MFMA. C[l,o]=xT.w1^T then bias+relu+pool -> h[b,c,lp]
__global__ __launch_bounds__(256) void k1_gemm(
    const unsigned short* __restrict__ xT, const unsigned short* __restrict__ w1b,
    const float* __restrict__ b1, unsigned short* __restrict__ h)
{
    const int nt = blockIdx.x & 1;
    const int g  = (blockIdx.x >> 1) & 1;
    const int rt = blockIdx.x >> 2;
    const int r0 = rt * 128;               // row over (b,l)
    const int b  = r0 >> 11, l0 = r0 & 2047;
    const int c0 = g * 256 + nt * 128;

    __shared__ unsigned short Asl[128 * BK];
    __shared__ unsigned short Bsl[128 * BK];
    __shared__ unsigned short epi[128 * 72];

    const int t = threadIdx.x;
    const int lane = t & 63;
    const int wave = t >> 6;
    const int wm = wave & 1, wn = wave >> 1;
    const int q = lane >> 4, lm = lane & 15;

    f32x4 acc[4][4];
    #pragma unroll
    for (int i = 0; i < 4; ++i)
        #pragma unroll
        for (int j = 0; j < 4; ++j)
            #pragma unroll
            for (int r = 0; r < 4; ++r) acc[i][j][r] = 0.f;

    for (int k0 = 0; k0 < 128; k0 += BK) {
        #pragma unroll
        for (int rd = 0; rd < 4; ++rd) {
            const int e = rd * 2048 + t * 8;
            const int row = e >> 6, col = e & 63;
            const unsigned short* ga = xT + (size_t)(r0 + row) * 256 + g * 128 + k0 + col;
            __builtin_amdgcn_global_load_lds((gas_u32*)ga, (las_u32*)(Asl + e), 16, 0, 0);
            const unsigned short* gb = w1b + (size_t)(c0 + row) * 128 + k0 + col;
            __builtin_amdgcn_global_load_lds((gas_u32*)gb, (las_u32*)(Bsl + e), 16, 0, 0);
        }
        __syncthreads();
        #pragma unroll
        for (int kk = 0; kk < 2; ++kk) {
            bf16x8 af[4], bf[4];
            #pragma unroll
            for (int i = 0; i < 4; ++i)
                af[i] = *(const bf16x8*)(Asl + (wm * 64 + i * 16 + lm) * BK + kk * 32 + q * 8);
            #pragma unroll
            for (int j = 0; j < 4; ++j)
                bf[j] = *(const bf16x8*)(Bsl + (wn * 64 + j * 16 + lm) * BK + kk * 32 + q * 8);
            #pragma unroll
            for (int i = 0; i < 4; ++i)
                #pragma unroll
                for (int j = 0; j < 4; ++j)
                    acc[i][j] = __builtin_amdgcn_mfma_f32_16x16x32_bf16(af[i], bf[j], acc[i][j], 0, 0, 0);
        }
        __syncthreads();
    }

    // epilogue: bias + relu + pool(adjacent C rows) -> LDS [c][lp] -> coalesced store
    #pragma unroll
    for (int j = 0; j < 4; ++j) {
        const int c_blk = wn * 64 + j * 16 + lm;
        const float bias = b1[c0 + c_blk];
        #pragma unroll
        for (int i = 0; i < 4; ++i) {
            const float p0 = fmaxf(fmaxf(acc[i][j][0], acc[i][j][1]) + bias, 0.f);
            const float p1 = fmaxf(fmaxf(acc[i][j][2], acc[i][j][3]) + bias, 0.f);
            const int lp_blk = wm * 32 + i * 8 + q * 2;
            ushort2 u; u.x = f2bf(p0); u.y = f2bf(p1);
            *(ushort2*)(epi + c_blk * 72 + lp_blk) = u;
        }
    }
    __syncthreads();
    const int c_blk = t >> 1, half = t & 1;
    unsigned short* dst = h + ((size_t)(b * 512 + c0 + c_blk)) * 1024 + (l0 >> 1) + half * 32;
    #pragma unroll
    for (int u = 0; u < 4; ++u)
        *(u16x8*)(dst + u * 8) = *(const u16x8*)(epi + c_blk * 72 + half * 32 + u * 8);
}

// ---------------- gemm_bt: C[M,N] fp32 = A[M,K]bf16 . B[N,K]bf16^T  (scores)
__global__ __launch_bounds__(256) void gemm_bt(
    const unsigned short* __restrict__ A, const unsigned short* __restrict__ B,
    float* __restrict__ C, int M, int N, int K, int ntiles)
{
    const int nt = blockIdx.x % ntiles;
    const int rt = blockIdx.x / ntiles;
    const int r0 = rt * 128, n0 = nt * 128;

    __shared__ unsigned short Asl[128 * BK];
    __shared__ unsigned short Bsl[128 * BK];

    const int t = threadIdx.x;
    const int lane = t & 63;
    const int wave = t >> 6;
    const int wm = wave & 1, wn = wave >> 1;
    const int q = lane >> 4, lm = lane & 15;

    f32x4 acc[4][4];
    #pragma unroll
    for (int i = 0; i < 4; ++i)
        #pragma unroll
        for (int j = 0; j < 4; ++j)
            #pragma unroll
            for (int r = 0; r < 4; ++r) acc[i][j][r] = 0.f;

    for (int k0 = 0; k0 < K; k0 += BK) {
        #pragma unroll
        for (int rd = 0; rd < 4; ++rd) {
            const int e = rd * 2048 + t * 8;
            const int row = e >> 6, col = e & 63;
            const unsigned short* ga = A + (size_t)(r0 + row) * K + k0 + col;
            __builtin_amdgcn_global_load_lds((gas_u32*)ga, (las_u32*)(Asl + e), 16, 0, 0);
            const unsigned short* gb = B + (size_t)(n0 + row) * K + k0 + col;
            __builtin_amdgcn_global_load_lds((gas_u32*)gb, (las_u32*)(Bsl + e), 16, 0, 0);
        }
        __syncthreads();
        #pragma unroll
        for (int kk = 0; kk < 2; ++kk) {
            bf16x8 af[4], bf[4];
            #pragma unroll
            for (int i = 0; i < 4; ++i)
                af[i] = *(const bf16x8*)(Asl + (wm * 64 + i * 16 + lm) * BK + kk * 32 + q * 8);
            #pragma unroll
            for (int j = 0; j < 4; ++j)
                bf[j] = *(const bf16x8*)(Bsl + (wn * 64 + j * 16 + lm) * BK + kk * 32 + q * 8);
            #pragma unroll
            for (int i = 0; i < 4; ++i)
                #pragma unroll
                for (int j = 0; j < 4; ++j)
                    acc[i][j] = __builtin_amdgcn_mfma_f32_16x16x32_bf16(af[i], bf[j], acc[i][j], 0, 0, 0);
        }
        __syncthreads();
    }

    #pragma unroll
    for (int i = 0; i < 4; ++i)
        #pragma unroll
        for (int j = 0; j < 4; ++j)
            #pragma unroll
            for (int r = 0; r < 4; ++r)
                C[(size_t)(r0 + wm * 64 + i * 16 + q * 4 + r) * N + n0 + wn * 64 + j * 16 + lm] = acc[i][j][r];
}

// ---------------- softmax over M=512, S fp32 -> Ab bf16 (8192 rows)
__global__ __launch_bounds__(256) void k_softmax(
    const float* __restrict__ S, unsigned short* __restrict__ Ab)
{
    const int row = blockIdx.x * 4 + (threadIdx.x >> 6);
    const int lane = threadIdx.x & 63;
    const float* p = S + (size_t)row * 512;
    unsigned short* po = Ab + (size_t)row * 512;

    float v[8];
    #pragma unroll
    for (int j = 0; j < 8; ++j) v[j] = p[lane + 64 * j];

    float mx = v[0];
    #pragma unroll
    for (int j = 1; j < 8; ++j) mx = fmaxf(mx, v[j]);
    for (int off = 32; off > 0; off >>= 1) mx = fmaxf(mx, __shfl_xor(mx, off));

    float sum = 0.f;
    #pragma unroll
    for (int j = 0; j < 8; ++j) { v[j] = __expf(v[j] - mx); sum += v[j]; }
    for (int off = 32; off > 0; off >>= 1) sum += __shfl_xor(sum, off);

    const float inv = 1.f / sum;
    #pragma unroll
    for (int j = 0; j < 8; ++j) po[lane + 64 * j] = f2bf(v[j] * inv);
}

// ---------------- gemm_retr: per-batch h2T[b,lp,c] bf16 = Ptb[lp,m] . attn_b[c,m]^T
__global__ __launch_bounds__(256) void gemm_retr(
    const unsigned short* __restrict__ Ptb, const unsigned short* __restrict__ Ab,
    unsigned short* __restrict__ h2T)
{
    const int tl = blockIdx.x & 31;
    const int b  = blockIdx.x >> 5;
    const int nt = tl & 3;
    const int rt = tl >> 2;
    const int r0 = rt * 128, n0 = nt * 128;

    __shared__ unsigned short Asl[128 * BK];
    __shared__ unsigned short Bsl[128 * BK];

    const int t = threadIdx.x;
    const int lane = t & 63;
    const int wave = t >> 6;
    const int wm = wave & 1, wn = wave >> 1;
    const int q = lane >> 4, lm = lane & 15;

    f32x4 acc[4][4];
    #pragma unroll
    for (int i = 0; i < 4; ++i)
        #pragma unroll
        for (int j = 0; j < 4; ++j)
            #pragma unroll
            for (int r = 0; r < 4; ++r) acc[i][j][r] = 0.f;

    for (int k0 = 0; k0 < 512; k0 += BK) {
        #pragma unroll
        for (int rd = 0; rd < 4; ++rd) {
            const int e = rd * 2048 + t * 8;
            const int row = e >> 6, col = e & 63;
            const unsigned short* ga = Ptb + (size_t)(r0 + row) * 512 + k0 + col;
            __builtin_amdgcn_global_load_lds((gas_u32*)ga, (las_u32*)(Asl + e), 16, 0, 0);
            const unsigned short* gb = Ab + ((size_t)b * 512 + n0 + row) * 512 + k0 + col;
            __builtin_amdgcn_global_load_lds((gas_u32*)gb, (las_u32*)(Bsl + e), 16, 0, 0);
        }
        __syncthreads();
        #pragma unroll
        for (int kk = 0; kk < 2; ++kk) {
            bf16x8 af[4], bf[4];
            #pragma unroll
            for (int i = 0; i < 4; ++i)
                af[i] = *(const bf16x8*)(Asl + (wm * 64 + i * 16 + lm) * BK + kk * 32 + q * 8);
            #pragma unroll
            for (int j = 0; j < 4; ++j)
                bf[j] = *(const bf16x8*)(Bsl + (wn * 64 + j * 16 + lm) * BK + kk * 32 + q * 8);
            #pragma unroll
            for (int i = 0; i < 4; ++i)
                #pragma unroll
                for (int j = 0; j < 4; ++j)
                    acc[i][j] = __builtin_amdgcn_mfma_f32_16x16x32_bf16(af[i], bf[j], acc[i][j], 0, 0, 0);
        }
        __syncthreads();
    }

    #pragma unroll
    for (int i = 0; i < 4; ++i)
        #pragma unroll
        for (int j = 0; j < 4; ++j)
            #pragma unroll
            for (int r = 0; r < 4; ++r)
                h2T[((size_t)b * 1024 + r0 + wm * 64 + i * 16 + q * 4 + r) * 512
                    + n0 + wn * 64 + j * 16 + lm] = f2bf(acc[i][j][r]);
}

// ---------------- k4_gemm: convT via MFMA. C[(b,lp),(o,kk)] = h2T . wTt^T, fused epilogue
__global__ __launch_bounds__(256) void k4_gemm(
    const unsigned short* __restrict__ h2T, const unsigned short* __restrict__ wTt,
    const float* __restrict__ bT, const float* __restrict__ x,
    const float* __restrict__ RZ, float* __restrict__ out)
{
    const int nt = blockIdx.x & 1;
    const int g  = (blockIdx.x >> 1) & 1;
    const int rt = blockIdx.x >> 2;
    const int r0 = rt * 128;               // row over (b,lp)
    const int b  = r0 >> 10, lp0 = r0 & 1023;

    __shared__ __align__(16) char smem[65536];
    unsigned short* Asl = (unsigned short*)smem;
    unsigned short* Bsl = Asl + 128 * BK;
    float* epi = (float*)smem;             // 64 x 256 f32 (swizzled), reused after K loop

    const int t = threadIdx.x;
    const int lane = t & 63;
    const int wave = t >> 6;
    const int wm = wave & 1, wn = wave >> 1;
    const int q = lane >> 4, lm = lane & 15;

    f32x4 acc[4][4];
    #pragma unroll
    for (int i = 0; i < 4; ++i)
        #pragma unroll
        for (int j = 0; j < 4; ++j)
            #pragma unroll
            for (int r = 0; r < 4; ++r) acc[i][j][r] = 0.f;

    for (int k0 = 0; k0 < 256; k0 += BK) {
        #pragma unroll
        for (int rd = 0; rd < 4; ++rd) {
            const int e = rd * 2048 + t * 8;
            const int row = e >> 6, col = e & 63;
            const unsigned short* ga = h2T + (size_t)(r0 + row) * 512 + g * 256 + k0 + col;
            __builtin_amdgcn_global_load_lds((gas_u32*)ga, (las_u32*)(Asl + e), 16, 0, 0);
            const unsigned short* gb = wTt + (size_t)g * 65536 + (size_t)(nt * 128 + row) * 256 + k0 + col;
            __builtin_amdgcn_global_load_lds((gas_u32*)gb, (las_u32*)(Bsl + e), 16, 0, 0);
        }
        __syncthreads();
        #pragma unroll
        for (int kk = 0; kk < 2; ++kk) {
            bf16x8 af[4], bf[4];
            #pragma unroll
            for (int i = 0; i < 4; ++i)
                af[i] = *(const bf16x8*)(Asl + (wm * 64 + i * 16 + lm) * BK + kk * 32 + q * 8);
            #pragma unroll
            for (int j = 0; j < 4; ++j)
                bf[j] = *(const bf16x8*)(Bsl + (wn * 64 + j * 16 + lm) * BK + kk * 32 + q * 8);
            #pragma unroll
            for (int i = 0; i < 4; ++i)
                #pragma unroll
                for (int j = 0; j < 4; ++j)
                    acc[i][j] = __builtin_amdgcn_mfma_f32_16x16x32_bf16(af[i], bf[j], acc[i][j], 0, 0, 0);
        }
        __syncthreads();
    }

    // epilogue: acc -> swizzled LDS [o][l], then bias+relu+RZ+residual, coalesced f32 out
    #pragma unroll
    for (int j = 0; j < 4; ++j) {
        const int col_blk = wn * 64 + j * 16 + lm;
        const int o_l = col_blk >> 1, kk2 = col_blk & 1;
        #pragma unroll
        for (int i = 0; i < 4; ++i) {
            #pragma unroll
            for (int r = 0; r < 4; ++r) {
                const int row_l = wm * 64 + i * 16 + q * 4 + r;
                const int l_l = 2 * row_l + kk2;
                const int chunk = ((l_l >> 2) + o_l) & 63;
                epi[o_l * 256 + chunk * 4 + (l_l & 3)] = acc[i][j][r];
            }
        }
    }
    __syncthreads();
    const int row = t >> 2, quad = t & 3;
    const int c = g * 128 + nt * 64 + row;
    const float bias = bT[c];
    const float rz = RZ[0];
    const size_t gbase = ((size_t)(b * 256 + c)) * 2048 + 2 * lp0 + quad * 64;
    #pragma unroll
    for (int k = 0; k < 16; ++k) {
        const int chunk_phys = (quad * 16 + k + row) & 63;
        const float4 v = *(const float4*)(epi + row * 256 + chunk_phys * 4);
        const float4 xv = *(const float4*)(x + gbase + k * 4);
        float4 o;
        o.x = xv.x + rz * fmaxf(v.x + bias, 0.f);
        o.y = xv.y + rz * fmaxf(v.y + bias, 0.f);
        o.z = xv.z + rz * fmaxf(v.z + bias, 0.f);
        o.w = xv.w + rz * fmaxf(v.w + bias, 0.f);
        *(float4*)(out + gbase + k * 4) = o;
    }
}

extern "C" void kernel_launch(void* const* d_in, const int* in_sizes, int n_in,
                              void* d_out, int out_size, void* d_ws, size_t ws_size,
                              hipStream_t stream) {
    (void)in_sizes; (void)n_in; (void)out_size; (void)ws_size;
    const float* x  = (const float*)d_in[0];
    const float* w1 = (const float*)d_in[1];
    const float* b1 = (const float*)d_in[2];
    const float* P  = (const float*)d_in[3];
    const float* wT = (const float*)d_in[4];
    const float* bT = (const float*)d_in[5];
    const float* RZ = (const float*)d_in[6];
    float* out = (float*)d_out;

    // workspace (34.5 MB):
    //   [0,16M)   xT bf16 [16,2048,256]  (k0->k1), then h2T bf16 [16,1024,512] (gemm_retr->k4)
    //   [16,32M)  hb bf16 [8192,1024]    (k1->gemm1), then Ab bf16 [8192,512] (softmax->gemm_retr)
    //   [32M..)   Pb 1M, Ptb 1M, w1b 128K, wTt 256K
    // S fp32 [8192,512] (16 MB) lives in d_out (dead before k4 overwrites out).
    char* ws = (char*)d_ws;
    unsigned short* xT  = (unsigned short*)ws;
    unsigned short* h2T = (unsigned short*)ws;
    unsigned short* hb  = (unsigned short*)(ws + (16u << 20));
    unsigned short* Ab  = (unsigned short*)(ws + (16u << 20));
    unsigned short* Pb  = (unsigned short*)(ws + (32u << 20));
    unsigned short* Ptb = (unsigned short*)(ws + (33u << 20));
    unsigned short* w1b = (unsigned short*)(ws + (34u << 20));
    unsigned short* wTt = (unsigned short*)(ws + (34u << 20) + (256u << 10));
    float* S = out;

    hipLaunchKernelGGL(k_prep,    dim3(128),  dim3(256), 0, stream, P, Pb, Ptb);
    hipLaunchKernelGGL(k_prep2,   dim3(512),  dim3(256), 0, stream, w1, wT, w1b, wTt);
    hipLaunchKernelGGL(k0_xT,     dim3(2048), dim3(256), 0, stream, x, xT);
    hipLaunchKernelGGL(k1_gemm,   dim3(1024), dim3(256), 0, stream, xT, w1b, b1, hb);
    hipLaunchKernelGGL(gemm_bt,   dim3(256),  dim3(256), 0, stream, hb, Pb, S,
                       8192, 512, 1024, 4);
    hipLaunchKernelGGL(k_softmax, dim3(2048), dim3(256), 0, stream, S, Ab);
    hipLaunchKernelGGL(gemm_retr, dim3(512),  dim3(256), 0, stream, Ptb, Ab, h2T);
    hipLaunchKernelGGL(k4_gemm,   dim3(512),  dim3(256), 0, stream, h2T, wTt, bT, x, RZ, out);
}

// Round 4
// 186.873 us; speedup vs baseline: 2.8686x; 1.0031x over previous
//
#include <hip/hip_runtime.h>

#define NB 16
#define NCIN 256
#define NL 2048
#define NHID 512
#define NM 512
#define NLP 1024
#define BK 64

typedef short bf16x8 __attribute__((ext_vector_type(8)));
typedef unsigned short u16x8 __attribute__((ext_vector_type(8)));
typedef float f32x4 __attribute__((ext_vector_type(4)));
typedef __attribute__((address_space(1))) const unsigned int gas_u32;
typedef __attribute__((address_space(3))) unsigned int las_u32;

__device__ __forceinline__ unsigned short f2bf(float f) {
    unsigned int u = __builtin_bit_cast(unsigned int, f);
    return (unsigned short)((u + 0x7FFFu + ((u >> 16) & 1u)) >> 16);
}
__device__ __forceinline__ float bf2f(unsigned short u) {
    return __builtin_bit_cast(float, ((unsigned int)u) << 16);
}

// ---------------- prep (merged): P cast+transpose, w1 cast, wT transpose+cast
__global__ __launch_bounds__(256) void k_prep(
    const float* __restrict__ P, const float* __restrict__ w1,
    const float* __restrict__ wT, unsigned short* __restrict__ Pb,
    unsigned short* __restrict__ Ptb, unsigned short* __restrict__ w1b,
    unsigned short* __restrict__ wTt)
{
    __shared__ unsigned short tbuf[64][65];
    const int bb = blockIdx.x;
    if (bb < 128) {
        const int mt = bb >> 4;
        const int lt = bb & 15;
        for (int i = threadIdx.x; i < 4096; i += 256) {
            const int r = i >> 6, c = i & 63;
            const unsigned short b = f2bf(P[(size_t)(mt * 64 + r) * 1024 + lt * 64 + c]);
            Pb[(size_t)(mt * 64 + r) * 1024 + lt * 64 + c] = b;
            tbuf[c][r] = b;
        }
        __syncthreads();
        for (int i = threadIdx.x; i < 4096; i += 256) {
            const int r = i >> 6, c = i & 63;
            Ptb[(size_t)(lt * 64 + r) * 512 + mt * 64 + c] = tbuf[r][c];
        }
    } else {
        const int t = (bb - 128) * 256 + threadIdx.x;
        if (t < 65536) w1b[t] = f2bf(w1[t]);
        if (t < 131072) {
            const int g = t >> 16, ok = (t >> 8) & 255, i = t & 255;
            wTt[t] = f2bf(wT[((size_t)(g * 256 + i)) * 256 + ok]);
        }
    }
}

// ---------------- k0: x fp32 [b,256,2048] -> xT bf16 [b,2048,256]
__global__ __launch_bounds__(256) void k0_xT(
    const float* __restrict__ x, unsigned short* __restrict__ xT)
{
    const int ct = blockIdx.x & 3;
    const int lt = (blockIdx.x >> 2) & 31;
    const int b  = blockIdx.x >> 7;
    __shared__ float tile[64 * 68];
    const int t = threadIdx.x;
    #pragma unroll
    for (int it = 0; it < 4; ++it) {
        const int idx = t + it * 256;
        const int ch = idx >> 4, f4 = idx & 15;
        const float4 v = *(const float4*)(x + ((size_t)(b * 256 + ct * 64 + ch)) * 2048 + lt * 64 + f4 * 4);
        *(float4*)(tile + ch * 68 + f4 * 4) = v;
    }
    __syncthreads();
    const int l = t >> 2, cq = t & 3;
    u16x8 o0, o1;
    #pragma unroll
    for (int k = 0; k < 8; ++k) o0[k] = f2bf(tile[(cq * 16 + k) * 68 + l]);
    #pragma unroll
    for (int k = 0; k < 8; ++k) o1[k] = f2bf(tile[(cq * 16 + 8 + k) * 68 + l]);
    unsigned short* dst = xT + ((size_t)(b * 2048 + lt * 64 + l)) * 256 + ct * 64 + cq * 16;
    *(u16x8*)dst = o0;
    *(u16x8*)(dst + 8) = o1;
}

// ---------------- k1_gemm: conv1x1 via MFMA. C[l,o]=xT.w1^T then bias+relu+pool -> h[b,c,lp]
__global__ __launch_bounds__(256) void k1_gemm(
    const unsigned short* __restrict__ xT, const unsigned short* __restrict__ w1b,
    const float* __restrict__ b1, unsigned short* __restrict__ h)
{
    const int nt = blockIdx.x & 1;
    const int g  = (blockIdx.x >> 1) & 1;
    const int rt = blockIdx.x >> 2;
    const int r0 = rt * 128;               // row over (b,l)
    const int b  = r0 >> 11, l0 = r0 & 2047;
    const int c0 = g * 256 + nt * 128;

    __shared__ unsigned short Asl[128 * BK];
    __shared__ unsigned short Bsl[128 * BK];
    __shared__ unsigned short epi[128 * 72];

    const int t = threadIdx.x;
    const int lane = t & 63;
    const int wave = t >> 6;
    const int wm = wave & 1, wn = wave >> 1;
    const int q = lane >> 4, lm = lane & 15;

    f32x4 acc[4][4];
    #pragma unroll
    for (int i = 0; i < 4; ++i)
        #pragma unroll
        for (int j = 0; j < 4; ++j)
            #pragma unroll
            for (int r = 0; r < 4; ++r) acc[i][j][r] = 0.f;

    for (int k0 = 0; k0 < 128; k0 += BK) {
        #pragma unroll
        for (int rd = 0; rd < 4; ++rd) {
            const int e = rd * 2048 + t * 8;
            const int row = e >> 6, col = e & 63;
            const unsigned short* ga = xT + (size_t)(r0 + row) * 256 + g * 128 + k0 + col;
            __builtin_amdgcn_global_load_lds((gas_u32*)ga, (las_u32*)(Asl + e), 16, 0, 0);
            const unsigned short* gb = w1b + (size_t)(c0 + row) * 128 + k0 + col;
            __builtin_amdgcn_global_load_lds((gas_u32*)gb, (las_u32*)(Bsl + e), 16, 0, 0);
        }
        __syncthreads();
        #pragma unroll
        for (int kk = 0; kk < 2; ++kk) {
            bf16x8 af[4], bf[4];
            #pragma unroll
            for (int i = 0; i < 4; ++i)
                af[i] = *(const bf16x8*)(Asl + (wm * 64 + i * 16 + lm) * BK + kk * 32 + q * 8);
            #pragma unroll
            for (int j = 0; j < 4; ++j)
                bf[j] = *(const bf16x8*)(Bsl + (wn * 64 + j * 16 + lm) * BK + kk * 32 + q * 8);
            #pragma unroll
            for (int i = 0; i < 4; ++i)
                #pragma unroll
                for (int j = 0; j < 4; ++j)
                    acc[i][j] = __builtin_amdgcn_mfma_f32_16x16x32_bf16(af[i], bf[j], acc[i][j], 0, 0, 0);
        }
        __syncthreads();
    }

    #pragma unroll
    for (int j = 0; j < 4; ++j) {
        const int c_blk = wn * 64 + j * 16 + lm;
        const float bias = b1[c0 + c_blk];
        #pragma unroll
        for (int i = 0; i < 4; ++i) {
            const float p0 = fmaxf(fmaxf(acc[i][j][0], acc[i][j][1]) + bias, 0.f);
            const float p1 = fmaxf(fmaxf(acc[i][j][2], acc[i][j][3]) + bias, 0.f);
            const int lp_blk = wm * 32 + i * 8 + q * 2;
            ushort2 u; u.x = f2bf(p0); u.y = f2bf(p1);
            *(ushort2*)(epi + c_blk * 72 + lp_blk) = u;
        }
    }
    __syncthreads();
    const int c_blk = t >> 1, half = t & 1;
    unsigned short* dst = h + ((size_t)(b * 512 + c0 + c_blk)) * 1024 + (l0 >> 1) + half * 32;
    #pragma unroll
    for (int u = 0; u < 4; ++u)
        *(u16x8*)(dst + u * 8) = *(const u16x8*)(epi + c_blk * 72 + half * 32 + u * 8);
}

// ---------------- gemm_sc: Sb[8192,512] bf16 = hb . Pb^T   (512 thr, 8 waves)
__global__ __launch_bounds__(512, 2) void gemm_sc(
    const unsigned short* __restrict__ A, const unsigned short* __restrict__ B,
    unsigned short* __restrict__ Sb)
{
    const int nt = blockIdx.x & 3;
    const int rt = blockIdx.x >> 2;
    const int r0 = rt * 128, n0 = nt * 128;

    __shared__ unsigned short Asl[128 * BK];
    __shared__ unsigned short Bsl[128 * BK];

    const int t = threadIdx.x;
    const int lane = t & 63;
    const int wave = t >> 6;                 // 0..7
    const int wm = wave & 1, wn = wave >> 1; // row half (64), col quarter (32)
    const int q = lane >> 4, lm = lane & 15;

    f32x4 acc[4][2];
    #pragma unroll
    for (int i = 0; i < 4; ++i)
        #pragma unroll
        for (int j = 0; j < 2; ++j)
            #pragma unroll
            for (int r = 0; r < 4; ++r) acc[i][j][r] = 0.f;

    for (int k0 = 0; k0 < 1024; k0 += BK) {
        #pragma unroll
        for (int rd = 0; rd < 2; ++rd) {
            const int e = rd * 4096 + t * 8;
            const int row = e >> 6, col = e & 63;
            const unsigned short* ga = A + (size_t)(r0 + row) * 1024 + k0 + col;
            __builtin_amdgcn_global_load_lds((gas_u32*)ga, (las_u32*)(Asl + e), 16, 0, 0);
            const unsigned short* gb = B + (size_t)(n0 + row) * 1024 + k0 + col;
            __builtin_amdgcn_global_load_lds((gas_u32*)gb, (las_u32*)(Bsl + e), 16, 0, 0);
        }
        __syncthreads();
        #pragma unroll
        for (int kk = 0; kk < 2; ++kk) {
            bf16x8 af[4], bf[2];
            #pragma unroll
            for (int i = 0; i < 4; ++i)
                af[i] = *(const bf16x8*)(Asl + (wm * 64 + i * 16 + lm) * BK + kk * 32 + q * 8);
            #pragma unroll
            for (int j = 0; j < 2; ++j)
                bf[j] = *(const bf16x8*)(Bsl + (wn * 32 + j * 16 + lm) * BK + kk * 32 + q * 8);
            #pragma unroll
            for (int i = 0; i < 4; ++i)
                #pragma unroll
                for (int j = 0; j < 2; ++j)
                    acc[i][j] = __builtin_amdgcn_mfma_f32_16x16x32_bf16(af[i], bf[j], acc[i][j], 0, 0, 0);
        }
        __syncthreads();
    }

    #pragma unroll
    for (int i = 0; i < 4; ++i)
        #pragma unroll
        for (int j = 0; j < 2; ++j)
            #pragma unroll
            for (int r = 0; r < 4; ++r)
                Sb[(size_t)(r0 + wm * 64 + i * 16 + q * 4 + r) * 512
                   + n0 + wn * 32 + j * 16 + lm] = f2bf(acc[i][j][r]);
}

// ---------------- softmax over M=512, Sb bf16 -> Ab bf16 (8192 rows)
__global__ __launch_bounds__(256) void k_softmax(
    const unsigned short* __restrict__ Sb, unsigned short* __restrict__ Ab)
{
    const int row = blockIdx.x * 4 + (threadIdx.x >> 6);
    const int lane = threadIdx.x & 63;
    const u16x8 uv = *(const u16x8*)(Sb + (size_t)row * 512 + lane * 8);

    float v[8];
    #pragma unroll
    for (int j = 0; j < 8; ++j) v[j] = bf2f(uv[j]);

    float mx = v[0];
    #pragma unroll
    for (int j = 1; j < 8; ++j) mx = fmaxf(mx, v[j]);
    for (int off = 32; off > 0; off >>= 1) mx = fmaxf(mx, __shfl_xor(mx, off));

    float sum = 0.f;
    #pragma unroll
    for (int j = 0; j < 8; ++j) { v[j] = __expf(v[j] - mx); sum += v[j]; }
    for (int off = 32; off > 0; off >>= 1) sum += __shfl_xor(sum, off);

    const float inv = 1.f / sum;
    u16x8 ov;
    #pragma unroll
    for (int j = 0; j < 8; ++j) ov[j] = f2bf(v[j] * inv);
    *(u16x8*)(Ab + (size_t)row * 512 + lane * 8) = ov;
}

// ---------------- gemm_retr: per-batch h2T[b,lp,c] bf16 = Ptb . attn_b^T (512 thr, 8 waves)
__global__ __launch_bounds__(512, 4) void gemm_retr(
    const unsigned short* __restrict__ Ptb, const unsigned short* __restrict__ Ab,
    unsigned short* __restrict__ h2T)
{
    const int tl = blockIdx.x & 31;
    const int b  = blockIdx.x >> 5;
    const int nt = tl & 3;
    const int rt = tl >> 2;
    const int r0 = rt * 128, n0 = nt * 128;

    __shared__ unsigned short Asl[128 * BK];
    __shared__ unsigned short Bsl[128 * BK];

    const int t = threadIdx.x;
    const int lane = t & 63;
    const int wave = t >> 6;
    const int wm = wave & 1, wn = wave >> 1;
    const int q = lane >> 4, lm = lane & 15;

    f32x4 acc[4][2];
    #pragma unroll
    for (int i = 0; i < 4; ++i)
        #pragma unroll
        for (int j = 0; j < 2; ++j)
            #pragma unroll
            for (int r = 0; r < 4; ++r) acc[i][j][r] = 0.f;

    for (int k0 = 0; k0 < 512; k0 += BK) {
        #pragma unroll
        for (int rd = 0; rd < 2; ++rd) {
            const int e = rd * 4096 + t * 8;
            const int row = e >> 6, col = e & 63;
            const unsigned short* ga = Ptb + (size_t)(r0 + row) * 512 + k0 + col;
            __builtin_amdgcn_global_load_lds((gas_u32*)ga, (las_u32*)(Asl + e), 16, 0, 0);
            const unsigned short* gb = Ab + ((size_t)b * 512 + n0 + row) * 512 + k0 + col;
            __builtin_amdgcn_global_load_lds((gas_u32*)gb, (las_u32*)(Bsl + e), 16, 0, 0);
        }
        __syncthreads();
        #pragma unroll
        for (int kk = 0; kk < 2; ++kk) {
            bf16x8 af[4], bf[2];
            #pragma unroll
            for (int i = 0; i < 4; ++i)
                af[i] = *(const bf16x8*)(Asl + (wm * 64 + i * 16 + lm) * BK + kk * 32 + q * 8);
            #pragma unroll
            for (int j = 0; j < 2; ++j)
                bf[j] = *(const bf16x8*)(Bsl + (wn * 32 + j * 16 + lm) * BK + kk * 32 + q * 8);
            #pragma unroll
            for (int i = 0; i < 4; ++i)
                #pragma unroll
                for (int j = 0; j < 2; ++j)
                    acc[i][j] = __builtin_amdgcn_mfma_f32_16x16x32_bf16(af[i], bf[j], acc[i][j], 0, 0, 0);
        }
        __syncthreads();
    }

    #pragma unroll
    for (int i = 0; i < 4; ++i)
        #pragma unroll
        for (int j = 0; j < 2; ++j)
            #pragma unroll
            for (int r = 0; r < 4; ++r)
                h2T[((size_t)b * 1024 + r0 + wm * 64 + i * 16 + q * 4 + r) * 512
                    + n0 + wn * 32 + j * 16 + lm] = f2bf(acc[i][j][r]);
}

// ---------------- k4_gemm: convT via MFMA. C[(b,lp),(o,kk)] = h2T . wTt^T, fused epilogue
__global__ __launch_bounds__(256) void k4_gemm(
    const unsigned short* __restrict__ h2T, const unsigned short* __restrict__ wTt,
    const float* __restrict__ bT, const float* __restrict__ x,
    const float* __restrict__ RZ, float* __restrict__ out)
{
    const int nt = blockIdx.x & 1;
    const int g  = (blockIdx.x >> 1) & 1;
    const int rt = blockIdx.x >> 2;
    const int r0 = rt * 128;               // row over (b,lp)
    const int b  = r0 >> 10, lp0 = r0 & 1023;

    __shared__ __align__(16) char smem[65536];
    unsigned short* Asl = (unsigned short*)smem;
    unsigned short* Bsl = Asl + 128 * BK;
    float* epi = (float*)smem;             // 64 x 256 f32 (swizzled), reused after K loop

    const int t = threadIdx.x;
    const int lane = t & 63;
    const int wave = t >> 6;
    const int wm = wave & 1, wn = wave >> 1;
    const int q = lane >> 4, lm = lane & 15;

    f32x4 acc[4][4];
    #pragma unroll
    for (int i = 0; i < 4; ++i)
        #pragma unroll
        for (int j = 0; j < 4; ++j)
            #pragma unroll
            for (int r = 0; r < 4; ++r) acc[i][j][r] = 0.f;

    for (int k0 = 0; k0 < 256; k0 += BK) {
        #pragma unroll
        for (int rd = 0; rd < 4; ++rd) {
            const int e = rd * 2048 + t * 8;
            const int row = e >> 6, col = e & 63;
            const unsigned short* ga = h2T + (size_t)(r0 + row) * 512 + g * 256 + k0 + col;
            __builtin_amdgcn_global_load_lds((gas_u32*)ga, (las_u32*)(Asl + e), 16, 0, 0);
            const unsigned short* gb = wTt + (size_t)g * 65536 + (size_t)(nt * 128 + row) * 256 + k0 + col;
            __builtin_amdgcn_global_load_lds((gas_u32*)gb, (las_u32*)(Bsl + e), 16, 0, 0);
        }
        __syncthreads();
        #pragma unroll
        for (int kk = 0; kk < 2; ++kk) {
            bf16x8 af[4], bf[4];
            #pragma unroll
            for (int i = 0; i < 4; ++i)
                af[i] = *(const bf16x8*)(Asl + (wm * 64 + i * 16 + lm) * BK + kk * 32 + q * 8);
            #pragma unroll
            for (int j = 0; j < 4; ++j)
                bf[j] = *(const bf16x8*)(Bsl + (wn * 64 + j * 16 + lm) * BK + kk * 32 + q * 8);
            #pragma unroll
            for (int i = 0; i < 4; ++i)
                #pragma unroll
                for (int j = 0; j < 4; ++j)
                    acc[i][j] = __builtin_amdgcn_mfma_f32_16x16x32_bf16(af[i], bf[j], acc[i][j], 0, 0, 0);
        }
        __syncthreads();
    }

    #pragma unroll
    for (int j = 0; j < 4; ++j) {
        const int col_blk = wn * 64 + j * 16 + lm;
        const int o_l = col_blk >> 1, kk2 = col_blk & 1;
        #pragma unroll
        for (int i = 0; i < 4; ++i) {
            #pragma unroll
            for (int r = 0; r < 4; ++r) {
                const int row_l = wm * 64 + i * 16 + q * 4 + r;
                const int l_l = 2 * row_l + kk2;
                const int chunk = ((l_l >> 2) + o_l) & 63;
                epi[o_l * 256 + chunk * 4 + (l_l & 3)] = acc[i][j][r];
            }
        }
    }
    __syncthreads();
    const int row = t >> 2, quad = t & 3;
    const int c = g * 128 + nt * 64 + row;
    const float bias = bT[c];
    const float rz = RZ[0];
    const size_t gbase = ((size_t)(b * 256 + c)) * 2048 + 2 * lp0 + quad * 64;
    #pragma unroll
    for (int k = 0; k < 16; ++k) {
        const int chunk_phys = (quad * 16 + k + row) & 63;
        const float4 v = *(const float4*)(epi + row * 256 + chunk_phys * 4);
        const float4 xv = *(const float4*)(x + gbase + k * 4);
        float4 o;
        o.x = xv.x + rz * fmaxf(v.x + bias, 0.f);
        o.y = xv.y + rz * fmaxf(v.y + bias, 0.f);
        o.z = xv.z + rz * fmaxf(v.z + bias, 0.f);
        o.w = xv.w + rz * fmaxf(v.w + bias, 0.f);
        *(float4*)(out + gbase + k * 4) = o;
    }
}

extern "C" void kernel_launch(void* const* d_in, const int* in_sizes, int n_in,
                              void* d_out, int out_size, void* d_ws, size_t ws_size,
                              hipStream_t stream) {
    (void)in_sizes; (void)n_in; (void)out_size; (void)ws_size;
    const float* x  = (const float*)d_in[0];
    const float* w1 = (const float*)d_in[1];
    const float* b1 = (const float*)d_in[2];
    const float* P  = (const float*)d_in[3];
    const float* wT = (const float*)d_in[4];
    const float* bT = (const float*)d_in[5];
    const float* RZ = (const float*)d_in[6];
    float* out = (float*)d_out;

    // workspace (34.5 MB):
    //   [0,16M)   xT bf16 [16,2048,256]  (k0->k1), then h2T bf16 [16,1024,512] (gemm_retr->k4)
    //   [16,32M)  hb bf16 [8192,1024]    (k1->gemm_sc), then Ab bf16 [8192,512] (softmax->gemm_retr)
    //   [32M..)   Pb 1M, Ptb 1M, w1b 128K, wTt 256K
    // Sb bf16 [8192,512] (8 MB) lives in d_out (dead before k4 overwrites out).
    char* ws = (char*)d_ws;
    unsigned short* xT  = (unsigned short*)ws;
    unsigned short* h2T = (unsigned short*)ws;
    unsigned short* hb  = (unsigned short*)(ws + (16u << 20));
    unsigned short* Ab  = (unsigned short*)(ws + (16u << 20));
    unsigned short* Pb  = (unsigned short*)(ws + (32u << 20));
    unsigned short* Ptb = (unsigned short*)(ws + (33u << 20));
    unsigned short* w1b = (unsigned short*)(ws + (34u << 20));
    unsigned short* wTt = (unsigned short*)(ws + (34u << 20) + (256u << 10));
    unsigned short* Sb  = (unsigned short*)out;

    hipLaunchKernelGGL(k_prep,    dim3(640),  dim3(256), 0, stream, P, w1, wT, Pb, Ptb, w1b, wTt);
    hipLaunchKernelGGL(k0_xT,     dim3(2048), dim3(256), 0, stream, x, xT);
    hipLaunchKernelGGL(k1_gemm,   dim3(1024), dim3(256), 0, stream, xT, w1b, b1, hb);
    hipLaunchKernelGGL(gemm_sc,   dim3(256),  dim3(512), 0, stream, hb, Pb, Sb);
    hipLaunchKernelGGL(k_softmax, dim3(2048), dim3(256), 0, stream, Sb, Ab);
    hipLaunchKernelGGL(gemm_retr, dim3(512),  dim3(512), 0, stream, Ptb, Ab, h2T);
    hipLaunchKernelGGL(k4_gemm,   dim3(512),  dim3(256), 0, stream, h2T, wTt, bT, x, RZ, out);
}